// Round 4
// baseline (898.747 us; speedup 1.0000x reference)
//
#include <hip/hip_runtime.h>
#include <math.h>

// ============================================================================
// CALIBRATION ROUND: every dispatch is launched TWICE (all kernels idempotent).
// dur' - dur_prev  = K  (true kernel+overhead time)
// 2*dur_prev - dur' = F (fixed per-replay cost outside our kernels)
// Kernels themselves are bit-identical to the 694.5us round-3 version.
// ============================================================================

typedef __attribute__((ext_vector_type(8))) short short8_t;
typedef __attribute__((ext_vector_type(4))) float f32x4;

#define Hh 512
#define Ww 512
#define IMG (Hh * Ww)
#define WINP 128
#define PP (WINP * WINP)
#define QS 325   // padded pixel-stride per q-slab (in 8-short units); 324 px used

__device__ __forceinline__ unsigned short f2bf(float f) {
    unsigned int u = __builtin_bit_cast(unsigned int, f);
    u += 0x7fffu + ((u >> 16) & 1u);
    return (unsigned short)(u >> 16);
}
__device__ __forceinline__ float bf2f(unsigned short h) {
    unsigned int u = ((unsigned int)h) << 16;
    return __builtin_bit_cast(float, u);
}

// ---------------- box (argmax) ----------------
__global__ void box_kernel(const float* __restrict__ pred, int* __restrict__ box) {
    int tid = threadIdx.x;
    float best = -1.0f; int bidx = 0x7fffffff;
    for (int cand = tid; cand < 51 * 51; cand += 256) {
        int i = cand / 51, j = cand % 51;
        int y = i * 10, x = j * 10;
        float T = 0.f, Bv = 0.f;
#pragma unroll
        for (int k = 0; k < 6; ++k) {
            T  += pred[((k * 3 + 0) * Hh + y) * Ww + x];
            Bv += pred[((k * 3 + 2) * Hh + y) * Ww + x];
        }
        float d = fabsf(1.0f - T - Bv / 6.0f);
        if (d > best || (d == best && cand < bidx)) { best = d; bidx = cand; }
    }
    __shared__ float sv[256];
    __shared__ int   si[256];
    sv[tid] = best; si[tid] = bidx;
    __syncthreads();
    for (int s = 128; s > 0; s >>= 1) {
        if (tid < s) {
            if (sv[tid + s] > sv[tid] || (sv[tid + s] == sv[tid] && si[tid + s] < si[tid])) {
                sv[tid] = sv[tid + s]; si[tid] = si[tid + s];
            }
        }
        __syncthreads();
    }
    if (tid == 0) {
        int idx = si[0];
        int cy = (idx / 51) * 10, cx = (idx % 51) * 10;
        int yy = cy - 64; yy = yy < 0 ? 0 : (yy > Hh - WINP ? Hh - WINP : yy);
        int xx = cx - 64; xx = xx < 0 ? 0 : (xx > Ww - WINP ? Ww - WINP : xx);
        box[0] = yy; box[1] = xx;
    }
}

// ---------------- copy pred -> out ----------------
__global__ void copy_kernel(const float4* __restrict__ src, float4* __restrict__ dst) {
    int i = blockIdx.x * 256 + threadIdx.x;
    dst[i] = src[i];
}

// ---------------- weight pre-swizzle into B-fragment order ----------------
__global__ void prep_weights(const float* __restrict__ sw, const float* __restrict__ m1w,
                             const float* __restrict__ m2w, const float* __restrict__ hw,
                             unsigned short* __restrict__ WF)
{
    int idx = blockIdx.x * 256 + threadIdx.x;   // < 175104 exactly
    int j = idx & 7;
    int lane = (idx >> 3) & 63;
    int frag = idx >> 9;
    int n16 = lane & 15;
    int ko = (lane >> 4) * 8 + j;
    float v = 0.f;
    if (frag < 108) {
        int g = frag / 36; int r = frag % 36; int kc = r / 18; r %= 18; int tap = r / 2; int nf = r & 1;
        int oc = g * 32 + nf * 16 + n16; int ic = kc * 32 + ko;
        v = sw[(oc * 64 + ic) * 9 + tap];
    } else if (frag < 252) {
        int r = frag - 108; int half = r / 72; r %= 72; int kc = r / 18; r %= 18; int tap = r / 2; int nf = r & 1;
        int oc = half * 32 + nf * 16 + n16; int ic = kc * 32 + ko;
        if (ic < 99) v = m1w[(oc * 99 + ic) * 9 + tap];
    } else if (frag < 324) {
        int r = frag - 252; int half = r / 36; r %= 36; int kc = r / 18; r %= 18; int tap = r / 2; int nf = r & 1;
        int oc = half * 32 + nf * 16 + n16; int ic = kc * 32 + ko;
        v = m2w[(oc * 64 + ic) * 9 + tap];
    } else {
        int r = frag - 324; int kc = r / 9; int tap = r % 9;
        int ic = kc * 32 + ko;
        if (n16 < 3) v = hw[(n16 * 64 + ic) * 9 + tap];
    }
    WF[idx] = f2bf(v);
}

// ---------------- feat patch -> channel-last bf16 ----------------
__global__ void prep_featcl(const float* __restrict__ feat, const int* __restrict__ box,
                            unsigned short* __restrict__ featcl)
{
    int row = blockIdx.x;   // 0..127
    int k = blockIdx.y;
    int t = threadIdx.x;
    int y1 = box[0], x1 = box[1];
    __shared__ unsigned short s[128 * 64];
    for (int i = 0; i < 32; ++i) {
        int idx = t + i * 256;
        int ic = idx >> 7, c = idx & 127;
        s[c * 64 + ic] = f2bf(feat[((size_t)(k * 64 + ic) * Hh + y1 + row) * Ww + x1 + c]);
    }
    __syncthreads();
    if (t < 128) {
        unsigned short* dst = &featcl[((size_t)k * 16384 + row * 128 + t) * 64];
        for (int i = 0; i < 8; ++i)
            *(short8_t*)&dst[i * 8] = *(short8_t*)&s[t * 64 + i * 8];
    }
}

// ---------------- split conv MFMA (grouped, attention-modulated) ----------------
__global__ __launch_bounds__(256) void split_mfma(
    const unsigned short* __restrict__ featcl, const float* __restrict__ pl,
    const unsigned short* __restrict__ WF, const float* __restrict__ sb,
    const int* __restrict__ box, unsigned short* __restrict__ fscl)
{
    const int tid = threadIdx.x;
    const int l = tid & 63, w = tid >> 6;
    const int T = blockIdx.x;
    const int k = blockIdx.y / 3, g = blockIdx.y % 3;
    const int ty0 = (T >> 3) * 16, tx0 = (T & 7) * 16;
    const int y1 = box[0], x1 = box[1];

    __shared__ __align__(16) unsigned short s_a[4 * QS * 8];   // 10400
    __shared__ __align__(16) unsigned short s_b[9216];         // 18*512

    f32x4 acc[4][2];
#pragma unroll
    for (int mf = 0; mf < 4; ++mf)
#pragma unroll
        for (int nf = 0; nf < 2; ++nf) acc[mf][nf] = (f32x4){0.f, 0.f, 0.f, 0.f};

    const float* plg = pl + (size_t)(k * 3 + g) * IMG + (size_t)y1 * Ww + x1;
    const unsigned short* fck = featcl + (size_t)k * 16384 * 64;

    for (int kc = 0; kc < 2; ++kc) {
        __syncthreads();
#pragma unroll
        for (int i = 0; i < 6; ++i) {
            int s = tid + i * 256;
            if (s < 1296) {
                int pxs = s >> 2, q = s & 3;
                int r = pxs / 18, c = pxs - r * 18;
                int py = ty0 - 1 + r, px = tx0 - 1 + c;
                short8_t o;
                if (py >= 0 && py < WINP && px >= 0 && px < WINP) {
                    float pv = plg[py * Ww + px];
                    short8_t f = *(const short8_t*)&fck[(size_t)(py * WINP + px) * 64 + kc * 32 + q * 8];
#pragma unroll
                    for (int e = 0; e < 8; ++e) o[e] = (short)f2bf(bf2f((unsigned short)f[e]) * pv);
                } else {
#pragma unroll
                    for (int e = 0; e < 8; ++e) o[e] = 0;
                }
                *(short8_t*)&s_a[(q * QS + pxs) * 8] = o;
            }
        }
        {
            const unsigned short* src = WF + (size_t)((g * 2 + kc) * 18) * 512;
#pragma unroll
            for (int i = 0; i < 5; ++i) {
                int cch = tid + i * 256;
                if (cch < 1152)
                    *(short8_t*)&s_b[cch * 8] = *(const short8_t*)&src[cch * 8];
            }
        }
        __syncthreads();
#pragma unroll
        for (int tap = 0; tap < 9; ++tap) {
            int dy = tap / 3, dx = tap % 3;
            short8_t a[4];
#pragma unroll
            for (int mf = 0; mf < 4; ++mf)
                a[mf] = *(const short8_t*)&s_a[((l >> 4) * QS + (w * 4 + mf + dy) * 18 + (l & 15) + dx) * 8];
#pragma unroll
            for (int nf = 0; nf < 2; ++nf) {
                short8_t bfr = *(const short8_t*)&s_b[((tap * 2 + nf) * 64 + l) * 8];
#pragma unroll
                for (int mf = 0; mf < 4; ++mf)
                    acc[mf][nf] = __builtin_amdgcn_mfma_f32_16x16x32_bf16(a[mf], bfr, acc[mf][nf], 0, 0, 0);
            }
        }
    }
    __syncthreads();
    unsigned short* s_t = s_a;
#pragma unroll
    for (int nf = 0; nf < 2; ++nf) {
        float bias = sb[g * 32 + nf * 16 + (l & 15)];
        int slot = nf * 2 + ((l & 15) >> 3);
#pragma unroll
        for (int mf = 0; mf < 4; ++mf) {
            int row = w * 4 + mf;
#pragma unroll
            for (int r = 0; r < 4; ++r) {
                int col = (l >> 4) * 4 + r;
                s_t[(slot * 256 + row * 16 + col) * 8 + (l & 7)] = f2bf(acc[mf][nf][r] + bias);
            }
        }
    }
    __syncthreads();
    {
        int row = tid >> 4, col = tid & 15;
        size_t gpx = (size_t)(ty0 + row) * WINP + tx0 + col;
        unsigned short* dst = fscl + ((size_t)k * 16384 + gpx) * 96 + g * 32;
#pragma unroll
        for (int i = 0; i < 4; ++i)
            *(short8_t*)&dst[i * 8] = *(short8_t*)&s_t[(i * 256 + tid) * 8];
    }
}

// ---------------- k-sum planes: T0 = S1/5 - S0, S0, B2 = S2/6 ----------------
__global__ void reduce_kernel(const unsigned short* __restrict__ fscl, float* __restrict__ Scl)
{
    int tg = blockIdx.x * 256 + threadIdx.x;  // < 65536
    int px = tg >> 2, q = tg & 3;
    float s0[8], s1[8], s2[8];
#pragma unroll
    for (int e = 0; e < 8; ++e) { s0[e] = 0.f; s1[e] = 0.f; s2[e] = 0.f; }
#pragma unroll
    for (int k = 0; k < 6; ++k) {
        const unsigned short* p = &fscl[((size_t)k * 16384 + px) * 96 + q * 8];
        short8_t a0 = *(const short8_t*)&p[0];
        short8_t a1 = *(const short8_t*)&p[32];
        short8_t a2 = *(const short8_t*)&p[64];
#pragma unroll
        for (int e = 0; e < 8; ++e) {
            s0[e] += bf2f((unsigned short)a0[e]);
            s1[e] += bf2f((unsigned short)a1[e]);
            s2[e] += bf2f((unsigned short)a2[e]);
        }
    }
    float* d = &Scl[(size_t)px * 96 + q * 8];
#pragma unroll
    for (int e = 0; e < 8; ++e) {
        d[e]      = s1[e] * 0.2f - s0[e];
        d[32 + e] = s0[e];
        d[64 + e] = s2[e] * (1.f / 6.f);
    }
}

// ---------------- merge1 MFMA (fused fcat combine in A-staging) ----------------
__global__ __launch_bounds__(256) void merge1_mfma(
    const unsigned short* __restrict__ fscl, const float* __restrict__ Scl,
    const float* __restrict__ x, const unsigned short* __restrict__ WF,
    const float* __restrict__ m1b, const int* __restrict__ box,
    unsigned short* __restrict__ h1cl)
{
    const int tid = threadIdx.x;
    const int l = tid & 63, w = tid >> 6;
    const int T = blockIdx.x;
    const int k = blockIdx.y >> 1, half = blockIdx.y & 1;
    const int ty0 = (T >> 3) * 16, tx0 = (T & 7) * 16;
    const int y1 = box[0], x1 = box[1];

    __shared__ __align__(16) unsigned short s_a[4 * QS * 8];
    __shared__ __align__(16) unsigned short s_b[9216];

    f32x4 acc[4][2];
#pragma unroll
    for (int mf = 0; mf < 4; ++mf)
#pragma unroll
        for (int nf = 0; nf < 2; ++nf) acc[mf][nf] = (f32x4){0.f, 0.f, 0.f, 0.f};

    for (int kc = 0; kc < 4; ++kc) {
        __syncthreads();
#pragma unroll
        for (int i = 0; i < 6; ++i) {
            int s = tid + i * 256;
            if (s < 1296) {
                int pxs = s >> 2, q = s & 3;
                int r = pxs / 18, c = pxs - r * 18;
                int py = ty0 - 1 + r, px = tx0 - 1 + c;
                short8_t o;
#pragma unroll
                for (int e = 0; e < 8; ++e) o[e] = 0;
                if (py >= 0 && py < WINP && px >= 0 && px < WINP) {
                    size_t gpx = (size_t)py * WINP + px;
                    if (kc == 0) {
                        short8_t f0 = *(const short8_t*)&fscl[((size_t)k * 16384 + gpx) * 96 + q * 8];
                        const float* S = &Scl[gpx * 96 + q * 8];
#pragma unroll
                        for (int e = 0; e < 8; ++e)
                            o[e] = (short)f2bf(S[e] + 2.f * bf2f((unsigned short)f0[e]));
                    } else if (kc == 1) {
                        const unsigned short* fp = &fscl[((size_t)k * 16384 + gpx) * 96];
                        short8_t f0 = *(const short8_t*)&fp[q * 8];
                        short8_t f1 = *(const short8_t*)&fp[32 + q * 8];
                        const float* S = &Scl[gpx * 96 + 32 + q * 8];
#pragma unroll
                        for (int e = 0; e < 8; ++e)
                            o[e] = (short)f2bf(S[e] - bf2f((unsigned short)f0[e]) + bf2f((unsigned short)f1[e]));
                    } else if (kc == 2) {
                        const float* S = &Scl[gpx * 96 + 64 + q * 8];
#pragma unroll
                        for (int e = 0; e < 8; ++e) o[e] = (short)f2bf(S[e]);
                    } else {
                        if (q == 0) {
#pragma unroll
                            for (int ch = 0; ch < 3; ++ch)
                                o[ch] = (short)f2bf(x[(size_t)(k * 3 + ch) * IMG + (size_t)(y1 + py) * Ww + x1 + px]);
                        }
                    }
                }
                *(short8_t*)&s_a[(q * QS + pxs) * 8] = o;
            }
        }
        {
            const unsigned short* src = WF + (size_t)(108 + (half * 4 + kc) * 18) * 512;
#pragma unroll
            for (int i = 0; i < 5; ++i) {
                int cch = tid + i * 256;
                if (cch < 1152)
                    *(short8_t*)&s_b[cch * 8] = *(const short8_t*)&src[cch * 8];
            }
        }
        __syncthreads();
#pragma unroll
        for (int tap = 0; tap < 9; ++tap) {
            int dy = tap / 3, dx = tap % 3;
            short8_t a[4];
#pragma unroll
            for (int mf = 0; mf < 4; ++mf)
                a[mf] = *(const short8_t*)&s_a[((l >> 4) * QS + (w * 4 + mf + dy) * 18 + (l & 15) + dx) * 8];
#pragma unroll
            for (int nf = 0; nf < 2; ++nf) {
                short8_t bfr = *(const short8_t*)&s_b[((tap * 2 + nf) * 64 + l) * 8];
#pragma unroll
                for (int mf = 0; mf < 4; ++mf)
                    acc[mf][nf] = __builtin_amdgcn_mfma_f32_16x16x32_bf16(a[mf], bfr, acc[mf][nf], 0, 0, 0);
            }
        }
    }
    __syncthreads();
    unsigned short* s_t = s_a;
#pragma unroll
    for (int nf = 0; nf < 2; ++nf) {
        float bias = m1b[half * 32 + nf * 16 + (l & 15)];
        int slot = nf * 2 + ((l & 15) >> 3);
#pragma unroll
        for (int mf = 0; mf < 4; ++mf) {
            int row = w * 4 + mf;
#pragma unroll
            for (int r = 0; r < 4; ++r) {
                int col = (l >> 4) * 4 + r;
                float v = acc[mf][nf][r] + bias;
                v = v >= 0.f ? v : 0.2f * v;
                s_t[(slot * 256 + row * 16 + col) * 8 + (l & 7)] = f2bf(v);
            }
        }
    }
    __syncthreads();
    {
        int row = tid >> 4, col = tid & 15;
        size_t gpx = (size_t)(ty0 + row) * WINP + tx0 + col;
        unsigned short* dst = h1cl + ((size_t)k * 16384 + gpx) * 64 + half * 32;
#pragma unroll
        for (int i = 0; i < 4; ++i)
            *(short8_t*)&dst[i * 8] = *(short8_t*)&s_t[(i * 256 + tid) * 8];
    }
}

// ---------------- merge2 MFMA ----------------
__global__ __launch_bounds__(256) void merge2_mfma(
    const unsigned short* __restrict__ h1cl, const unsigned short* __restrict__ WF,
    const float* __restrict__ m2b, unsigned short* __restrict__ h2cl)
{
    const int tid = threadIdx.x;
    const int l = tid & 63, w = tid >> 6;
    const int T = blockIdx.x;
    const int k = blockIdx.y >> 1, half = blockIdx.y & 1;
    const int ty0 = (T >> 3) * 16, tx0 = (T & 7) * 16;

    __shared__ __align__(16) unsigned short s_a[4 * QS * 8];
    __shared__ __align__(16) unsigned short s_b[9216];

    f32x4 acc[4][2];
#pragma unroll
    for (int mf = 0; mf < 4; ++mf)
#pragma unroll
        for (int nf = 0; nf < 2; ++nf) acc[mf][nf] = (f32x4){0.f, 0.f, 0.f, 0.f};

    const unsigned short* ink = h1cl + (size_t)k * 16384 * 64;

    for (int kc = 0; kc < 2; ++kc) {
        __syncthreads();
#pragma unroll
        for (int i = 0; i < 6; ++i) {
            int s = tid + i * 256;
            if (s < 1296) {
                int pxs = s >> 2, q = s & 3;
                int r = pxs / 18, c = pxs - r * 18;
                int py = ty0 - 1 + r, px = tx0 - 1 + c;
                short8_t o;
                if (py >= 0 && py < WINP && px >= 0 && px < WINP) {
                    o = *(const short8_t*)&ink[(size_t)(py * WINP + px) * 64 + kc * 32 + q * 8];
                } else {
#pragma unroll
                    for (int e = 0; e < 8; ++e) o[e] = 0;
                }
                *(short8_t*)&s_a[(q * QS + pxs) * 8] = o;
            }
        }
        {
            const unsigned short* src = WF + (size_t)(252 + (half * 2 + kc) * 18) * 512;
#pragma unroll
            for (int i = 0; i < 5; ++i) {
                int cch = tid + i * 256;
                if (cch < 1152)
                    *(short8_t*)&s_b[cch * 8] = *(const short8_t*)&src[cch * 8];
            }
        }
        __syncthreads();
#pragma unroll
        for (int tap = 0; tap < 9; ++tap) {
            int dy = tap / 3, dx = tap % 3;
            short8_t a[4];
#pragma unroll
            for (int mf = 0; mf < 4; ++mf)
                a[mf] = *(const short8_t*)&s_a[((l >> 4) * QS + (w * 4 + mf + dy) * 18 + (l & 15) + dx) * 8];
#pragma unroll
            for (int nf = 0; nf < 2; ++nf) {
                short8_t bfr = *(const short8_t*)&s_b[((tap * 2 + nf) * 64 + l) * 8];
#pragma unroll
                for (int mf = 0; mf < 4; ++mf)
                    acc[mf][nf] = __builtin_amdgcn_mfma_f32_16x16x32_bf16(a[mf], bfr, acc[mf][nf], 0, 0, 0);
            }
        }
    }
    __syncthreads();
    unsigned short* s_t = s_a;
#pragma unroll
    for (int nf = 0; nf < 2; ++nf) {
        float bias = m2b[half * 32 + nf * 16 + (l & 15)];
        int slot = nf * 2 + ((l & 15) >> 3);
#pragma unroll
        for (int mf = 0; mf < 4; ++mf) {
            int row = w * 4 + mf;
#pragma unroll
            for (int r = 0; r < 4; ++r) {
                int col = (l >> 4) * 4 + r;
                s_t[(slot * 256 + row * 16 + col) * 8 + (l & 7)] = f2bf(acc[mf][nf][r] + bias);
            }
        }
    }
    __syncthreads();
    {
        int row = tid >> 4, col = tid & 15;
        size_t gpx = (size_t)(ty0 + row) * WINP + tx0 + col;
        unsigned short* dst = h2cl + ((size_t)k * 16384 + gpx) * 64 + half * 32;
#pragma unroll
        for (int i = 0; i < 4; ++i)
            *(short8_t*)&dst[i * 8] = *(short8_t*)&s_t[(i * 256 + tid) * 8];
    }
}

// ---------------- head MFMA + tanh + scatter ----------------
__global__ __launch_bounds__(256) void head_mfma(
    const unsigned short* __restrict__ h2cl, const unsigned short* __restrict__ WF,
    const float* __restrict__ hb, const int* __restrict__ box,
    float* __restrict__ out)
{
    const int tid = threadIdx.x;
    const int l = tid & 63, w = tid >> 6;
    const int T = blockIdx.x;
    const int k = blockIdx.y;
    const int oy0 = 10 + (T / 7) * 16, ox0 = 10 + (T % 7) * 16;
    const int y1 = box[0], x1 = box[1];

    __shared__ __align__(16) unsigned short s_a[4 * QS * 8];
    __shared__ __align__(16) unsigned short s_b[4608];

    f32x4 acc[4];
#pragma unroll
    for (int mf = 0; mf < 4; ++mf) acc[mf] = (f32x4){0.f, 0.f, 0.f, 0.f};

    const unsigned short* ink = h2cl + (size_t)k * 16384 * 64;

    for (int kc = 0; kc < 2; ++kc) {
        __syncthreads();
#pragma unroll
        for (int i = 0; i < 6; ++i) {
            int s = tid + i * 256;
            if (s < 1296) {
                int pxs = s >> 2, q = s & 3;
                int r = pxs / 18, c = pxs - r * 18;
                int py = oy0 - 1 + r, px = ox0 - 1 + c;   // always in [9,122] -> in bounds
                *(short8_t*)&s_a[(q * QS + pxs) * 8] =
                    *(const short8_t*)&ink[(size_t)(py * WINP + px) * 64 + kc * 32 + q * 8];
            }
        }
        {
            const unsigned short* src = WF + (size_t)(324 + kc * 9) * 512;
#pragma unroll
            for (int i = 0; i < 3; ++i) {
                int cch = tid + i * 256;
                if (cch < 576)
                    *(short8_t*)&s_b[cch * 8] = *(const short8_t*)&src[cch * 8];
            }
        }
        __syncthreads();
#pragma unroll
        for (int tap = 0; tap < 9; ++tap) {
            int dy = tap / 3, dx = tap % 3;
            short8_t bfr = *(const short8_t*)&s_b[(tap * 64 + l) * 8];
#pragma unroll
            for (int mf = 0; mf < 4; ++mf) {
                short8_t a = *(const short8_t*)&s_a[((l >> 4) * QS + (w * 4 + mf + dy) * 18 + (l & 15) + dx) * 8];
                acc[mf] = __builtin_amdgcn_mfma_f32_16x16x32_bf16(a, bfr, acc[mf], 0, 0, 0);
            }
        }
    }
    int oc = l & 15;
    if (oc < 3) {
        float bias = hb[oc];
#pragma unroll
        for (int mf = 0; mf < 4; ++mf) {
            int row = oy0 + w * 4 + mf;
            if (row < 118) {
#pragma unroll
                for (int r = 0; r < 4; ++r) {
                    int col = ox0 + (l >> 4) * 4 + r;
                    if (col < 118) {
                        float v = (tanhf(acc[mf][r] + bias) + 1.0f) * 0.5f;
                        out[(size_t)(k * 3 + oc) * IMG + (size_t)(y1 + row) * Ww + x1 + col] = v;
                    }
                }
            }
        }
    }
}

extern "C" void kernel_launch(void* const* d_in, const int* in_sizes, int n_in,
                              void* d_out, int out_size, void* d_ws, size_t ws_size,
                              hipStream_t stream)
{
    const float* x       = (const float*)d_in[0];
    const float* pred    = (const float*)d_in[1];
    const float* feat    = (const float*)d_in[2];
    const float* split_w = (const float*)d_in[3];
    const float* split_b = (const float*)d_in[4];
    const float* m1w     = (const float*)d_in[5];
    const float* m1b     = (const float*)d_in[6];
    const float* m2w     = (const float*)d_in[7];
    const float* m2b     = (const float*)d_in[8];
    const float* hw      = (const float*)d_in[9];
    const float* hb      = (const float*)d_in[10];
    float* out = (float*)d_out;

    char* base = (char*)d_ws;
    size_t o = 0;
    int* box = (int*)(base + o);                  o += 256;
    unsigned short* WF = (unsigned short*)(base + o);      o += (size_t)175104 * 2;  o = (o + 255) & ~(size_t)255;
    unsigned short* featcl = (unsigned short*)(base + o);  o += (size_t)6 * 16384 * 64 * 2;
    unsigned short* fscl = (unsigned short*)(base + o);    o += (size_t)6 * 16384 * 96 * 2;
    float* Scl = (float*)(base + o);                       o += (size_t)16384 * 96 * 4;
    unsigned short* h1cl = (unsigned short*)(base + o);    o += (size_t)6 * 16384 * 64 * 2;
    unsigned short* h2cl = (unsigned short*)(base + o);    o += (size_t)6 * 16384 * 64 * 2;

    // ---- every dispatch duplicated (idempotent) : dur' - dur = true kernel time K ----
    box_kernel<<<1, 256, 0, stream>>>(pred, box);
    box_kernel<<<1, 256, 0, stream>>>(pred, box);
    prep_weights<<<684, 256, 0, stream>>>(split_w, m1w, m2w, hw, WF);
    prep_weights<<<684, 256, 0, stream>>>(split_w, m1w, m2w, hw, WF);
    prep_featcl<<<dim3(128, 6), 256, 0, stream>>>(feat, box, featcl);
    prep_featcl<<<dim3(128, 6), 256, 0, stream>>>(feat, box, featcl);
    copy_kernel<<<4608, 256, 0, stream>>>((const float4*)pred, (float4*)out);
    copy_kernel<<<4608, 256, 0, stream>>>((const float4*)pred, (float4*)out);

    for (int it = 0; it < 2; ++it) {
        split_mfma<<<dim3(64, 18), 256, 0, stream>>>(featcl, out, WF, split_b, box, fscl);
        split_mfma<<<dim3(64, 18), 256, 0, stream>>>(featcl, out, WF, split_b, box, fscl);
        reduce_kernel<<<256, 256, 0, stream>>>(fscl, Scl);
        reduce_kernel<<<256, 256, 0, stream>>>(fscl, Scl);
        merge1_mfma<<<dim3(64, 12), 256, 0, stream>>>(fscl, Scl, x, WF, m1b, box, h1cl);
        merge1_mfma<<<dim3(64, 12), 256, 0, stream>>>(fscl, Scl, x, WF, m1b, box, h1cl);
        merge2_mfma<<<dim3(64, 12), 256, 0, stream>>>(h1cl, WF, m2b, h2cl);
        merge2_mfma<<<dim3(64, 12), 256, 0, stream>>>(h1cl, WF, m2b, h2cl);
        head_mfma<<<dim3(49, 6), 256, 0, stream>>>(h2cl, WF, hb, box, out);
        head_mfma<<<dim3(49, 6), 256, 0, stream>>>(h2cl, WF, hb, box, out);
    }
}

// Round 5
// 658.252 us; speedup vs baseline: 1.3654x; 1.3654x over previous
//
#include <hip/hip_runtime.h>
#include <math.h>

typedef __attribute__((ext_vector_type(8))) short short8_t;
typedef __attribute__((ext_vector_type(4))) float f32x4;

#define Hh 512
#define Ww 512
#define IMG (Hh * Ww)
#define WINP 128
#define PP (WINP * WINP)
#define QS 325   // padded pixel-stride per q-slab (in 8-short units); 324 px used

__device__ __forceinline__ unsigned short f2bf(float f) {
    unsigned int u = __builtin_bit_cast(unsigned int, f);
    u += 0x7fffu + ((u >> 16) & 1u);
    return (unsigned short)(u >> 16);
}
__device__ __forceinline__ float bf2f(unsigned short h) {
    unsigned int u = ((unsigned int)h) << 16;
    return __builtin_bit_cast(float, u);
}

// ---------------- fused prologue: prep_weights | copy | box ----------------
// blocks [0,684): weights; [684,5292): copy pred->out; block 5292: box argmax.
__global__ void prologue_kernel(const float* __restrict__ pred, int* __restrict__ box,
                                const float* __restrict__ sw, const float* __restrict__ m1w,
                                const float* __restrict__ m2w, const float* __restrict__ hw,
                                unsigned short* __restrict__ WF,
                                const float4* __restrict__ csrc, float4* __restrict__ cdst)
{
    int b = blockIdx.x;
    int tid = threadIdx.x;
    if (b < 684) {
        // ---- weight pre-swizzle into B-fragment order ----
        int idx = b * 256 + tid;   // < 175104 exactly
        int j = idx & 7;
        int lane = (idx >> 3) & 63;
        int frag = idx >> 9;
        int n16 = lane & 15;
        int ko = (lane >> 4) * 8 + j;
        float v = 0.f;
        if (frag < 108) {
            int g = frag / 36; int r = frag % 36; int kc = r / 18; r %= 18; int tap = r / 2; int nf = r & 1;
            int oc = g * 32 + nf * 16 + n16; int ic = kc * 32 + ko;
            v = sw[(oc * 64 + ic) * 9 + tap];
        } else if (frag < 252) {
            int r = frag - 108; int half = r / 72; r %= 72; int kc = r / 18; r %= 18; int tap = r / 2; int nf = r & 1;
            int oc = half * 32 + nf * 16 + n16; int ic = kc * 32 + ko;
            if (ic < 99) v = m1w[(oc * 99 + ic) * 9 + tap];
        } else if (frag < 324) {
            int r = frag - 252; int half = r / 36; r %= 36; int kc = r / 18; r %= 18; int tap = r / 2; int nf = r & 1;
            int oc = half * 32 + nf * 16 + n16; int ic = kc * 32 + ko;
            v = m2w[(oc * 64 + ic) * 9 + tap];
        } else {
            int r = frag - 324; int kc = r / 9; int tap = r % 9;
            int ic = kc * 32 + ko;
            if (n16 < 3) v = hw[(n16 * 64 + ic) * 9 + tap];
        }
        WF[idx] = f2bf(v);
        return;
    }
    if (b < 5292) {
        int i = (b - 684) * 256 + tid;
        cdst[i] = csrc[i];
        return;
    }
    // ---- box (argmax) ----
    float best = -1.0f; int bidx = 0x7fffffff;
    for (int cand = tid; cand < 51 * 51; cand += 256) {
        int i = cand / 51, jj = cand % 51;
        int y = i * 10, x = jj * 10;
        float T = 0.f, Bv = 0.f;
#pragma unroll
        for (int k = 0; k < 6; ++k) {
            T  += pred[((k * 3 + 0) * Hh + y) * Ww + x];
            Bv += pred[((k * 3 + 2) * Hh + y) * Ww + x];
        }
        float d = fabsf(1.0f - T - Bv / 6.0f);
        if (d > best || (d == best && cand < bidx)) { best = d; bidx = cand; }
    }
    __shared__ float sv[256];
    __shared__ int   si[256];
    sv[tid] = best; si[tid] = bidx;
    __syncthreads();
    for (int s = 128; s > 0; s >>= 1) {
        if (tid < s) {
            if (sv[tid + s] > sv[tid] || (sv[tid + s] == sv[tid] && si[tid + s] < si[tid])) {
                sv[tid] = sv[tid + s]; si[tid] = si[tid + s];
            }
        }
        __syncthreads();
    }
    if (tid == 0) {
        int idx = si[0];
        int cy = (idx / 51) * 10, cx = (idx % 51) * 10;
        int yy = cy - 64; yy = yy < 0 ? 0 : (yy > Hh - WINP ? Hh - WINP : yy);
        int xx = cx - 64; xx = xx < 0 ? 0 : (xx > Ww - WINP ? Ww - WINP : xx);
        box[0] = yy; box[1] = xx;
    }
}

// ---------------- feat patch -> channel-last bf16 ----------------
__global__ void prep_featcl(const float* __restrict__ feat, const int* __restrict__ box,
                            unsigned short* __restrict__ featcl)
{
    int row = blockIdx.x;   // 0..127
    int k = blockIdx.y;
    int t = threadIdx.x;
    int y1 = box[0], x1 = box[1];
    __shared__ unsigned short s[128 * 64];
    for (int i = 0; i < 32; ++i) {
        int idx = t + i * 256;
        int ic = idx >> 7, c = idx & 127;
        s[c * 64 + ic] = f2bf(feat[((size_t)(k * 64 + ic) * Hh + y1 + row) * Ww + x1 + c]);
    }
    __syncthreads();
    if (t < 128) {
        unsigned short* dst = &featcl[((size_t)k * 16384 + row * 128 + t) * 64];
        for (int i = 0; i < 8; ++i)
            *(short8_t*)&dst[i * 8] = *(short8_t*)&s[t * 64 + i * 8];
    }
}

// ============================================================================
// MFMA kernels: wave owns 8 px-rows x 1 oc-half (nf = w&1, rbase = (w>>1)*8).
// Inner loop over input halo rows r (r = mf+dy): 3 dx-shifted A-frags loaded
// once per r, B (9 taps for this nf) hoisted to registers per kc.
// LDS reads per wave-kc: 30 A + 9 B (was 36 + 18).
// ============================================================================

// ---------------- split conv MFMA (grouped, attention-modulated) ----------------
// grid (64 tiles, 18 = k*3+g)
__global__ __launch_bounds__(256) void split_mfma(
    const unsigned short* __restrict__ featcl, const float* __restrict__ pl,
    const unsigned short* __restrict__ WF, const float* __restrict__ sb,
    const int* __restrict__ box, unsigned short* __restrict__ fscl)
{
    const int tid = threadIdx.x;
    const int l = tid & 63, w = tid >> 6;
    const int T = blockIdx.x;
    const int k = blockIdx.y / 3, g = blockIdx.y % 3;
    const int ty0 = (T >> 3) * 16, tx0 = (T & 7) * 16;
    const int y1 = box[0], x1 = box[1];
    const int nf = w & 1;
    const int rbase = (w >> 1) * 8;

    __shared__ __align__(16) unsigned short s_a[4 * QS * 8];   // 10400
    __shared__ __align__(16) unsigned short s_b[9216];         // 18*512

    f32x4 acc[8];
#pragma unroll
    for (int mf = 0; mf < 8; ++mf) acc[mf] = (f32x4){0.f, 0.f, 0.f, 0.f};

    const float* plg = pl + (size_t)(k * 3 + g) * IMG + (size_t)y1 * Ww + x1;
    const unsigned short* fck = featcl + (size_t)k * 16384 * 64;

    for (int kc = 0; kc < 2; ++kc) {
        __syncthreads();
#pragma unroll
        for (int i = 0; i < 6; ++i) {
            int s = tid + i * 256;
            if (s < 1296) {
                int pxs = s >> 2, q = s & 3;
                int r = pxs / 18, c = pxs - r * 18;
                int py = ty0 - 1 + r, px = tx0 - 1 + c;
                short8_t o;
                if (py >= 0 && py < WINP && px >= 0 && px < WINP) {
                    float pv = plg[py * Ww + px];
                    short8_t f = *(const short8_t*)&fck[(size_t)(py * WINP + px) * 64 + kc * 32 + q * 8];
#pragma unroll
                    for (int e = 0; e < 8; ++e) o[e] = (short)f2bf(bf2f((unsigned short)f[e]) * pv);
                } else {
#pragma unroll
                    for (int e = 0; e < 8; ++e) o[e] = 0;
                }
                *(short8_t*)&s_a[(q * QS + pxs) * 8] = o;
            }
        }
        {
            const unsigned short* src = WF + (size_t)((g * 2 + kc) * 18) * 512;
#pragma unroll
            for (int i = 0; i < 5; ++i) {
                int cch = tid + i * 256;
                if (cch < 1152)
                    *(short8_t*)&s_b[cch * 8] = *(const short8_t*)&src[cch * 8];
            }
        }
        __syncthreads();
        short8_t breg[9];
#pragma unroll
        for (int tap = 0; tap < 9; ++tap)
            breg[tap] = *(const short8_t*)&s_b[((tap * 2 + nf) * 64 + l) * 8];
#pragma unroll
        for (int r = 0; r < 10; ++r) {
            short8_t av[3];
#pragma unroll
            for (int dx = 0; dx < 3; ++dx)
                av[dx] = *(const short8_t*)&s_a[((l >> 4) * QS + (rbase + r) * 18 + (l & 15) + dx) * 8];
#pragma unroll
            for (int dy = 0; dy < 3; ++dy) {
                const int mf = r - dy;
                if (mf >= 0 && mf < 8) {
#pragma unroll
                    for (int dx = 0; dx < 3; ++dx)
                        acc[mf] = __builtin_amdgcn_mfma_f32_16x16x32_bf16(av[dx], breg[dy * 3 + dx], acc[mf], 0, 0, 0);
                }
            }
        }
    }
    __syncthreads();
    unsigned short* s_t = s_a;
    {
        float bias = sb[g * 32 + nf * 16 + (l & 15)];
        int slot = nf * 2 + ((l & 15) >> 3);
#pragma unroll
        for (int mf = 0; mf < 8; ++mf) {
            int row = rbase + mf;
#pragma unroll
            for (int r = 0; r < 4; ++r) {
                int col = (l >> 4) * 4 + r;
                s_t[(slot * 256 + row * 16 + col) * 8 + (l & 7)] = f2bf(acc[mf][r] + bias);
            }
        }
    }
    __syncthreads();
    {
        int row = tid >> 4, col = tid & 15;
        size_t gpx = (size_t)(ty0 + row) * WINP + tx0 + col;
        unsigned short* dst = fscl + ((size_t)k * 16384 + gpx) * 96 + g * 32;
#pragma unroll
        for (int i = 0; i < 4; ++i)
            *(short8_t*)&dst[i * 8] = *(short8_t*)&s_t[(i * 256 + tid) * 8];
    }
}

// ---------------- k-sum planes: T0 = S1/5 - S0, S0, B2 = S2/6 ----------------
__global__ void reduce_kernel(const unsigned short* __restrict__ fscl, float* __restrict__ Scl)
{
    int tg = blockIdx.x * 256 + threadIdx.x;  // < 65536
    int px = tg >> 2, q = tg & 3;
    float s0[8], s1[8], s2[8];
#pragma unroll
    for (int e = 0; e < 8; ++e) { s0[e] = 0.f; s1[e] = 0.f; s2[e] = 0.f; }
#pragma unroll
    for (int k = 0; k < 6; ++k) {
        const unsigned short* p = &fscl[((size_t)k * 16384 + px) * 96 + q * 8];
        short8_t a0 = *(const short8_t*)&p[0];
        short8_t a1 = *(const short8_t*)&p[32];
        short8_t a2 = *(const short8_t*)&p[64];
#pragma unroll
        for (int e = 0; e < 8; ++e) {
            s0[e] += bf2f((unsigned short)a0[e]);
            s1[e] += bf2f((unsigned short)a1[e]);
            s2[e] += bf2f((unsigned short)a2[e]);
        }
    }
    float* d = &Scl[(size_t)px * 96 + q * 8];
#pragma unroll
    for (int e = 0; e < 8; ++e) {
        d[e]      = s1[e] * 0.2f - s0[e];
        d[32 + e] = s0[e];
        d[64 + e] = s2[e] * (1.f / 6.f);
    }
}

// ---------------- merge1 MFMA (fused fcat combine in A-staging) ----------------
// grid (64, 12 = k*2+half). IC padded to 128 (4 kchunks; kc3 = x channels + zeros).
__global__ __launch_bounds__(256) void merge1_mfma(
    const unsigned short* __restrict__ fscl, const float* __restrict__ Scl,
    const float* __restrict__ x, const unsigned short* __restrict__ WF,
    const float* __restrict__ m1b, const int* __restrict__ box,
    unsigned short* __restrict__ h1cl)
{
    const int tid = threadIdx.x;
    const int l = tid & 63, w = tid >> 6;
    const int T = blockIdx.x;
    const int k = blockIdx.y >> 1, half = blockIdx.y & 1;
    const int ty0 = (T >> 3) * 16, tx0 = (T & 7) * 16;
    const int y1 = box[0], x1 = box[1];
    const int nf = w & 1;
    const int rbase = (w >> 1) * 8;

    __shared__ __align__(16) unsigned short s_a[4 * QS * 8];
    __shared__ __align__(16) unsigned short s_b[9216];

    f32x4 acc[8];
#pragma unroll
    for (int mf = 0; mf < 8; ++mf) acc[mf] = (f32x4){0.f, 0.f, 0.f, 0.f};

    for (int kc = 0; kc < 4; ++kc) {
        __syncthreads();
#pragma unroll
        for (int i = 0; i < 6; ++i) {
            int s = tid + i * 256;
            if (s < 1296) {
                int pxs = s >> 2, q = s & 3;
                int r = pxs / 18, c = pxs - r * 18;
                int py = ty0 - 1 + r, px = tx0 - 1 + c;
                short8_t o;
#pragma unroll
                for (int e = 0; e < 8; ++e) o[e] = 0;
                if (py >= 0 && py < WINP && px >= 0 && px < WINP) {
                    size_t gpx = (size_t)py * WINP + px;
                    if (kc == 0) {
                        short8_t f0 = *(const short8_t*)&fscl[((size_t)k * 16384 + gpx) * 96 + q * 8];
                        const float* S = &Scl[gpx * 96 + q * 8];
#pragma unroll
                        for (int e = 0; e < 8; ++e)
                            o[e] = (short)f2bf(S[e] + 2.f * bf2f((unsigned short)f0[e]));
                    } else if (kc == 1) {
                        const unsigned short* fp = &fscl[((size_t)k * 16384 + gpx) * 96];
                        short8_t f0 = *(const short8_t*)&fp[q * 8];
                        short8_t f1 = *(const short8_t*)&fp[32 + q * 8];
                        const float* S = &Scl[gpx * 96 + 32 + q * 8];
#pragma unroll
                        for (int e = 0; e < 8; ++e)
                            o[e] = (short)f2bf(S[e] - bf2f((unsigned short)f0[e]) + bf2f((unsigned short)f1[e]));
                    } else if (kc == 2) {
                        const float* S = &Scl[gpx * 96 + 64 + q * 8];
#pragma unroll
                        for (int e = 0; e < 8; ++e) o[e] = (short)f2bf(S[e]);
                    } else {
                        if (q == 0) {
#pragma unroll
                            for (int ch = 0; ch < 3; ++ch)
                                o[ch] = (short)f2bf(x[(size_t)(k * 3 + ch) * IMG + (size_t)(y1 + py) * Ww + x1 + px]);
                        }
                    }
                }
                *(short8_t*)&s_a[(q * QS + pxs) * 8] = o;
            }
        }
        {
            const unsigned short* src = WF + (size_t)(108 + (half * 4 + kc) * 18) * 512;
#pragma unroll
            for (int i = 0; i < 5; ++i) {
                int cch = tid + i * 256;
                if (cch < 1152)
                    *(short8_t*)&s_b[cch * 8] = *(const short8_t*)&src[cch * 8];
            }
        }
        __syncthreads();
        short8_t breg[9];
#pragma unroll
        for (int tap = 0; tap < 9; ++tap)
            breg[tap] = *(const short8_t*)&s_b[((tap * 2 + nf) * 64 + l) * 8];
#pragma unroll
        for (int r = 0; r < 10; ++r) {
            short8_t av[3];
#pragma unroll
            for (int dx = 0; dx < 3; ++dx)
                av[dx] = *(const short8_t*)&s_a[((l >> 4) * QS + (rbase + r) * 18 + (l & 15) + dx) * 8];
#pragma unroll
            for (int dy = 0; dy < 3; ++dy) {
                const int mf = r - dy;
                if (mf >= 0 && mf < 8) {
#pragma unroll
                    for (int dx = 0; dx < 3; ++dx)
                        acc[mf] = __builtin_amdgcn_mfma_f32_16x16x32_bf16(av[dx], breg[dy * 3 + dx], acc[mf], 0, 0, 0);
                }
            }
        }
    }
    __syncthreads();
    unsigned short* s_t = s_a;
    {
        float bias = m1b[half * 32 + nf * 16 + (l & 15)];
        int slot = nf * 2 + ((l & 15) >> 3);
#pragma unroll
        for (int mf = 0; mf < 8; ++mf) {
            int row = rbase + mf;
#pragma unroll
            for (int r = 0; r < 4; ++r) {
                int col = (l >> 4) * 4 + r;
                float v = acc[mf][r] + bias;
                v = v >= 0.f ? v : 0.2f * v;
                s_t[(slot * 256 + row * 16 + col) * 8 + (l & 7)] = f2bf(v);
            }
        }
    }
    __syncthreads();
    {
        int row = tid >> 4, col = tid & 15;
        size_t gpx = (size_t)(ty0 + row) * WINP + tx0 + col;
        unsigned short* dst = h1cl + ((size_t)k * 16384 + gpx) * 64 + half * 32;
#pragma unroll
        for (int i = 0; i < 4; ++i)
            *(short8_t*)&dst[i * 8] = *(short8_t*)&s_t[(i * 256 + tid) * 8];
    }
}

// ---------------- merge2 MFMA ----------------
// grid (64, 12 = k*2+half). IC=64, 2 kchunks.
__global__ __launch_bounds__(256) void merge2_mfma(
    const unsigned short* __restrict__ h1cl, const unsigned short* __restrict__ WF,
    const float* __restrict__ m2b, unsigned short* __restrict__ h2cl)
{
    const int tid = threadIdx.x;
    const int l = tid & 63, w = tid >> 6;
    const int T = blockIdx.x;
    const int k = blockIdx.y >> 1, half = blockIdx.y & 1;
    const int ty0 = (T >> 3) * 16, tx0 = (T & 7) * 16;
    const int nf = w & 1;
    const int rbase = (w >> 1) * 8;

    __shared__ __align__(16) unsigned short s_a[4 * QS * 8];
    __shared__ __align__(16) unsigned short s_b[9216];

    f32x4 acc[8];
#pragma unroll
    for (int mf = 0; mf < 8; ++mf) acc[mf] = (f32x4){0.f, 0.f, 0.f, 0.f};

    const unsigned short* ink = h1cl + (size_t)k * 16384 * 64;

    for (int kc = 0; kc < 2; ++kc) {
        __syncthreads();
#pragma unroll
        for (int i = 0; i < 6; ++i) {
            int s = tid + i * 256;
            if (s < 1296) {
                int pxs = s >> 2, q = s & 3;
                int r = pxs / 18, c = pxs - r * 18;
                int py = ty0 - 1 + r, px = tx0 - 1 + c;
                short8_t o;
                if (py >= 0 && py < WINP && px >= 0 && px < WINP) {
                    o = *(const short8_t*)&ink[(size_t)(py * WINP + px) * 64 + kc * 32 + q * 8];
                } else {
#pragma unroll
                    for (int e = 0; e < 8; ++e) o[e] = 0;
                }
                *(short8_t*)&s_a[(q * QS + pxs) * 8] = o;
            }
        }
        {
            const unsigned short* src = WF + (size_t)(252 + (half * 2 + kc) * 18) * 512;
#pragma unroll
            for (int i = 0; i < 5; ++i) {
                int cch = tid + i * 256;
                if (cch < 1152)
                    *(short8_t*)&s_b[cch * 8] = *(const short8_t*)&src[cch * 8];
            }
        }
        __syncthreads();
        short8_t breg[9];
#pragma unroll
        for (int tap = 0; tap < 9; ++tap)
            breg[tap] = *(const short8_t*)&s_b[((tap * 2 + nf) * 64 + l) * 8];
#pragma unroll
        for (int r = 0; r < 10; ++r) {
            short8_t av[3];
#pragma unroll
            for (int dx = 0; dx < 3; ++dx)
                av[dx] = *(const short8_t*)&s_a[((l >> 4) * QS + (rbase + r) * 18 + (l & 15) + dx) * 8];
#pragma unroll
            for (int dy = 0; dy < 3; ++dy) {
                const int mf = r - dy;
                if (mf >= 0 && mf < 8) {
#pragma unroll
                    for (int dx = 0; dx < 3; ++dx)
                        acc[mf] = __builtin_amdgcn_mfma_f32_16x16x32_bf16(av[dx], breg[dy * 3 + dx], acc[mf], 0, 0, 0);
                }
            }
        }
    }
    __syncthreads();
    unsigned short* s_t = s_a;
    {
        float bias = m2b[half * 32 + nf * 16 + (l & 15)];
        int slot = nf * 2 + ((l & 15) >> 3);
#pragma unroll
        for (int mf = 0; mf < 8; ++mf) {
            int row = rbase + mf;
#pragma unroll
            for (int r = 0; r < 4; ++r) {
                int col = (l >> 4) * 4 + r;
                s_t[(slot * 256 + row * 16 + col) * 8 + (l & 7)] = f2bf(acc[mf][r] + bias);
            }
        }
    }
    __syncthreads();
    {
        int row = tid >> 4, col = tid & 15;
        size_t gpx = (size_t)(ty0 + row) * WINP + tx0 + col;
        unsigned short* dst = h2cl + ((size_t)k * 16384 + gpx) * 64 + half * 32;
#pragma unroll
        for (int i = 0; i < 4; ++i)
            *(short8_t*)&dst[i * 8] = *(short8_t*)&s_t[(i * 256 + tid) * 8];
    }
}

// ---------------- head MFMA + tanh + scatter ----------------
// grid (49 = 7x7 tiles over [10,118), 6 = k). NF=1 (16 oc, 3 real).
__global__ __launch_bounds__(256) void head_mfma(
    const unsigned short* __restrict__ h2cl, const unsigned short* __restrict__ WF,
    const float* __restrict__ hb, const int* __restrict__ box,
    float* __restrict__ out)
{
    const int tid = threadIdx.x;
    const int l = tid & 63, w = tid >> 6;
    const int T = blockIdx.x;
    const int k = blockIdx.y;
    const int oy0 = 10 + (T / 7) * 16, ox0 = 10 + (T % 7) * 16;
    const int y1 = box[0], x1 = box[1];

    __shared__ __align__(16) unsigned short s_a[4 * QS * 8];
    __shared__ __align__(16) unsigned short s_b[4608];

    f32x4 acc[4];
#pragma unroll
    for (int mf = 0; mf < 4; ++mf) acc[mf] = (f32x4){0.f, 0.f, 0.f, 0.f};

    const unsigned short* ink = h2cl + (size_t)k * 16384 * 64;

    for (int kc = 0; kc < 2; ++kc) {
        __syncthreads();
#pragma unroll
        for (int i = 0; i < 6; ++i) {
            int s = tid + i * 256;
            if (s < 1296) {
                int pxs = s >> 2, q = s & 3;
                int r = pxs / 18, c = pxs - r * 18;
                int py = oy0 - 1 + r, px = ox0 - 1 + c;   // always in [9,122] -> in bounds
                *(short8_t*)&s_a[(q * QS + pxs) * 8] =
                    *(const short8_t*)&ink[(size_t)(py * WINP + px) * 64 + kc * 32 + q * 8];
            }
        }
        {
            const unsigned short* src = WF + (size_t)(324 + kc * 9) * 512;
#pragma unroll
            for (int i = 0; i < 3; ++i) {
                int cch = tid + i * 256;
                if (cch < 576)
                    *(short8_t*)&s_b[cch * 8] = *(const short8_t*)&src[cch * 8];
            }
        }
        __syncthreads();
        short8_t breg[9];
#pragma unroll
        for (int tap = 0; tap < 9; ++tap)
            breg[tap] = *(const short8_t*)&s_b[(tap * 64 + l) * 8];
#pragma unroll
        for (int r = 0; r < 6; ++r) {
            short8_t av[3];
#pragma unroll
            for (int dx = 0; dx < 3; ++dx)
                av[dx] = *(const short8_t*)&s_a[((l >> 4) * QS + (w * 4 + r) * 18 + (l & 15) + dx) * 8];
#pragma unroll
            for (int dy = 0; dy < 3; ++dy) {
                const int mf = r - dy;
                if (mf >= 0 && mf < 4) {
#pragma unroll
                    for (int dx = 0; dx < 3; ++dx)
                        acc[mf] = __builtin_amdgcn_mfma_f32_16x16x32_bf16(av[dx], breg[dy * 3 + dx], acc[mf], 0, 0, 0);
                }
            }
        }
    }
    int oc = l & 15;
    if (oc < 3) {
        float bias = hb[oc];
#pragma unroll
        for (int mf = 0; mf < 4; ++mf) {
            int row = oy0 + w * 4 + mf;
            if (row < 118) {
#pragma unroll
                for (int r = 0; r < 4; ++r) {
                    int col = ox0 + (l >> 4) * 4 + r;
                    if (col < 118) {
                        float v = (tanhf(acc[mf][r] + bias) + 1.0f) * 0.5f;
                        out[(size_t)(k * 3 + oc) * IMG + (size_t)(y1 + row) * Ww + x1 + col] = v;
                    }
                }
            }
        }
    }
}

extern "C" void kernel_launch(void* const* d_in, const int* in_sizes, int n_in,
                              void* d_out, int out_size, void* d_ws, size_t ws_size,
                              hipStream_t stream)
{
    const float* x       = (const float*)d_in[0];
    const float* pred    = (const float*)d_in[1];
    const float* feat    = (const float*)d_in[2];
    const float* split_w = (const float*)d_in[3];
    const float* split_b = (const float*)d_in[4];
    const float* m1w     = (const float*)d_in[5];
    const float* m1b     = (const float*)d_in[6];
    const float* m2w     = (const float*)d_in[7];
    const float* m2b     = (const float*)d_in[8];
    const float* hw      = (const float*)d_in[9];
    const float* hb      = (const float*)d_in[10];
    float* out = (float*)d_out;

    char* base = (char*)d_ws;
    size_t o = 0;
    int* box = (int*)(base + o);                  o += 256;
    unsigned short* WF = (unsigned short*)(base + o);      o += (size_t)175104 * 2;  o = (o + 255) & ~(size_t)255;
    unsigned short* featcl = (unsigned short*)(base + o);  o += (size_t)6 * 16384 * 64 * 2;
    unsigned short* fscl = (unsigned short*)(base + o);    o += (size_t)6 * 16384 * 96 * 2;
    float* Scl = (float*)(base + o);                       o += (size_t)16384 * 96 * 4;
    unsigned short* h1cl = (unsigned short*)(base + o);    o += (size_t)6 * 16384 * 64 * 2;
    unsigned short* h2cl = (unsigned short*)(base + o);    o += (size_t)6 * 16384 * 64 * 2;

    prologue_kernel<<<5293, 256, 0, stream>>>(pred, box, split_w, m1w, m2w, hw, WF,
                                              (const float4*)pred, (float4*)out);
    prep_featcl<<<dim3(128, 6), 256, 0, stream>>>(feat, box, featcl);

    for (int it = 0; it < 2; ++it) {
        split_mfma<<<dim3(64, 18), 256, 0, stream>>>(featcl, out, WF, split_b, box, fscl);
        reduce_kernel<<<256, 256, 0, stream>>>(fscl, Scl);
        merge1_mfma<<<dim3(64, 12), 256, 0, stream>>>(fscl, Scl, x, WF, m1b, box, h1cl);
        merge2_mfma<<<dim3(64, 12), 256, 0, stream>>>(h1cl, WF, m2b, h2cl);
        head_mfma<<<dim3(49, 6), 256, 0, stream>>>(h2cl, WF, hb, box, out);
    }
}